// Round 1
// baseline (1257.260 us; speedup 1.0000x reference)
//
#include <hip/hip_runtime.h>
#include <hip/hip_bf16.h>
#include <stdint.h>

// Problem constants (fixed by reference)
#define H_K   2048
#define VV    128256
#define NROWS 1024
#define SOFTCAP_F   30.0f
#define LS_EPS      0.1f
#define ZLOSS_SCALE 1e-4f
#define IGNORE_IDX  (-100)

// GEMM tiling
#define BM 128
#define BN 128
#define BK 64
#define NKT (H_K / BK)   // 32

typedef __attribute__((ext_vector_type(8))) short bf16x8;   // 8 bf16 = 4 VGPRs
typedef __attribute__((ext_vector_type(4))) float f32x4;

__device__ __forceinline__ short f2bf(float f) {
    __hip_bfloat16 h = __float2bfloat16(f);
    return __builtin_bit_cast(short, h);
}

__device__ __forceinline__ void gload_lds16(const void* g, void* l) {
    __builtin_amdgcn_global_load_lds(
        (const __attribute__((address_space(1))) unsigned*)g,
        (__attribute__((address_space(3))) unsigned*)l,
        16, 0, 0);
}

// ---------------- x fp32 -> bf16 conversion (4 MB, trivially mem-bound) -------------
__global__ void cvt_x_kernel(const float* __restrict__ x, short* __restrict__ xb, int n4) {
    int i = blockIdx.x * blockDim.x + threadIdx.x;
    if (i >= n4) return;
    float4 v = ((const float4*)x)[i];
    short4 h;
    h.x = f2bf(v.x); h.y = f2bf(v.y); h.z = f2bf(v.z); h.w = f2bf(v.w);
    ((short4*)xb)[i] = h;
}

// ---------------- fused GEMM + softcap + partial reductions ----------------
// C = x[1024,2048] * W^T[2048,128256], bf16 MFMA 16x16x32, fp32 acc.
// Per block: 128x128 logit tile. 4 waves (2x2), each 64x64.
// A tile (x): bf16 in ws, staged via global_load_lds w/ pre-swizzled source addr.
// B tile (W): fp32 in HBM, reg-staged with fused fp32->bf16 cvt, swizzled ds_write.
// LDS XOR-swizzle: byte ^= ((row&7)<<4)  (T2, G4: 128B-row tiles are 32-way conflict)
__global__ __launch_bounds__(256, 2)
void gemm_fused(const float* __restrict__ W,
                const short* __restrict__ xb,
                const int* __restrict__ y,
                float* __restrict__ ws_se,
                float* __restrict__ ws_sl,
                float* __restrict__ ws_zy)
{
    __shared__ short As[BM * BK];   // 16 KB, swizzled
    __shared__ short Bs[BN * BK];   // 16 KB, swizzled

    const int tid  = threadIdx.x;
    const int lane = tid & 63;
    const int wid  = tid >> 6;          // 0..3
    const int wm   = wid >> 1;          // wave row  (0..1)
    const int wn   = wid & 1;           // wave col  (0..1)

    const int bid  = blockIdx.x;
    const int mblk = bid & 7;           // NROWS/BM = 8  (m inner -> W-tile L2/L3 reuse)
    const int nblk = bid >> 3;          // 0..1001
    const int row0 = mblk * BM;
    const int col0 = nblk * BN;

    // ---- A staging setup: 4 global_load_lds (16B/lane) per K-step per thread ----
    // segment s = j*4 + wid (1 KB each); lds byte b = s*1024 + lane*16
    // LDS linear; SOURCE address pre-swizzled so LDS holds swizzled layout.
    uintptr_t a_g[4];
    void*     a_lb[4];
    #pragma unroll
    for (int j = 0; j < 4; ++j) {
        int s    = j * 4 + wid;
        int b    = s * 1024 + lane * 16;
        int rowt = b >> 7;                               // tile-local row
        int kb   = (b & 127) ^ ((rowt & 7) << 4);        // pre-swizzled k-byte
        a_g[j]  = (uintptr_t)((const char*)xb + (size_t)(row0 + rowt) * (H_K * 2) + kb);
        a_lb[j] = (char*)As + s * 1024;                  // wave-uniform base
    }

    // ---- B staging setup: 8x float4 loads + cvt + swizzled ds_write per K-step ----
    // flat fp32 byte o = (j*256 + tid)*16; row = o>>8; kf = o&255
    uintptr_t b_g[8];
    int       b_l[8];
    #pragma unroll
    for (int j = 0; j < 8; ++j) {
        int o    = (j * 256 + tid) * 16;
        int rowt = o >> 8;
        int kf   = o & 255;
        b_g[j] = (uintptr_t)((const char*)W + (size_t)(col0 + rowt) * (H_K * 4) + kf);
        int kb = (kf >> 1) ^ ((rowt & 7) << 4);          // bf16 byte, swizzled
        b_l[j] = rowt * 128 + kb;
    }

    f32x4 acc[4][4] = {};

    const int lrow = lane & 15;
    const int lkg  = lane >> 4;                 // 0..3
    const int swz  = (lrow & 7) << 4;
    char* AsB = (char*)As;
    char* BsB = (char*)Bs;

    for (int kt = 0; kt < NKT; ++kt) {
        // issue W loads first (latency), then A-tile DMA
        float4 wv[8];
        #pragma unroll
        for (int j = 0; j < 8; ++j) wv[j] = *(const float4*)(b_g[j]);
        #pragma unroll
        for (int j = 0; j < 4; ++j) gload_lds16((const void*)a_g[j], a_lb[j]);
        // cvt fp32->bf16 and write swizzled B tile
        #pragma unroll
        for (int j = 0; j < 8; ++j) {
            short4 h;
            h.x = f2bf(wv[j].x); h.y = f2bf(wv[j].y);
            h.z = f2bf(wv[j].z); h.w = f2bf(wv[j].w);
            *(short4*)(BsB + b_l[j]) = h;
        }
        __syncthreads();   // drains vmcnt (gload_lds) + lgkm (ds_write)

        #pragma unroll
        for (int ks = 0; ks < 2; ++ks) {
            bf16x8 af[4], bfv[4];
            #pragma unroll
            for (int m = 0; m < 4; ++m)
                af[m] = *(const bf16x8*)(AsB + (wm * 64 + m * 16 + lrow) * 128
                                             + ((ks * 64 + lkg * 16) ^ swz));
            #pragma unroll
            for (int n = 0; n < 4; ++n)
                bfv[n] = *(const bf16x8*)(BsB + (wn * 64 + n * 16 + lrow) * 128
                                              + ((ks * 64 + lkg * 16) ^ swz));
            #pragma unroll
            for (int m = 0; m < 4; ++m)
                #pragma unroll
                for (int n = 0; n < 4; ++n)
                    acc[m][n] = __builtin_amdgcn_mfma_f32_16x16x32_bf16(
                                    af[m], bfv[n], acc[m][n], 0, 0, 0);
        }
        __syncthreads();

        #pragma unroll
        for (int j = 0; j < 4; ++j) a_g[j] += BK * 2;
        #pragma unroll
        for (int j = 0; j < 8; ++j) b_g[j] += BK * 4;
    }

    // ---- epilogue: softcap, z_y scatter, per-row partial sumexp / sumlogit ----
    // C/D layout (m89/m91-verified): col = lane&15, row = (lane>>4)*4 + j
    #pragma unroll
    for (int m = 0; m < 4; ++m)
        #pragma unroll
        for (int n = 0; n < 4; ++n)
            #pragma unroll
            for (int j = 0; j < 4; ++j) {
                float v = acc[m][n][j];
                float e = __expf(v * (1.0f / 15.0f));        // e^{2v/30}
                acc[m][n][j] = SOFTCAP_F - 60.0f / (e + 1.0f);  // 30*tanh(v/30)
            }

    const int colw0 = col0 + wn * 64;
    #pragma unroll
    for (int m = 0; m < 4; ++m) {
        #pragma unroll
        for (int j = 0; j < 4; ++j) {
            const int grow = row0 + wm * 64 + m * 16 + lkg * 4 + j;
            // target-logit scatter (single writer: exactly one (block,thread) owns it)
            int ty = y[grow];
            int tc = ty - colw0;
            if ((unsigned)tc < 64u && (tc & 15) == lrow) {
                int nt = tc >> 4;
                float zv = (nt == 0) ? acc[m][0][j] :
                           (nt == 1) ? acc[m][1][j] :
                           (nt == 2) ? acc[m][2][j] : acc[m][3][j];
                ws_zy[grow] = zv;
            }
            // per-row partials over this wave's 64 cols
            float se = 0.f, sl = 0.f;
            #pragma unroll
            for (int n = 0; n < 4; ++n) {
                float v = acc[m][n][j];
                sl += v;
                se += __expf(v);     // logits <= 30 -> no max-shift needed
            }
            #pragma unroll
            for (int d = 1; d < 16; d <<= 1) {
                se += __shfl_xor(se, d, 64);
                sl += __shfl_xor(sl, d, 64);
            }
            if (lrow == 0) {
                atomicAdd(&ws_se[grow], se);
                atomicAdd(&ws_sl[grow], sl);
            }
        }
    }
}

// ---------------- finalize: per-token loss + mean ----------------
__global__ void finalize_kernel(const float* __restrict__ ws_se,
                                const float* __restrict__ ws_sl,
                                const float* __restrict__ ws_zy,
                                const int* __restrict__ y,
                                float* __restrict__ out, int n)
{
    __shared__ float sL[16], sC[16];
    const int tid = threadIdx.x;
    float loss = 0.f, cnt = 0.f;
    if (tid < n) {
        int ty = y[tid];
        if (ty != IGNORE_IDX) {
            float lse = logf(ws_se[tid]);
            float ce  = lse - (1.0f - LS_EPS) * ws_zy[tid]
                          - (LS_EPS / (float)VV) * ws_sl[tid];
            loss = ce + ZLOSS_SCALE * lse * lse;
            cnt  = 1.f;
        }
    }
    #pragma unroll
    for (int d = 32; d >= 1; d >>= 1) {
        loss += __shfl_down(loss, d, 64);
        cnt  += __shfl_down(cnt,  d, 64);
    }
    const int w = tid >> 6;
    if ((tid & 63) == 0) { sL[w] = loss; sC[w] = cnt; }
    __syncthreads();
    if (tid == 0) {
        float L = 0.f, C = 0.f;
        #pragma unroll
        for (int i = 0; i < 16; ++i) { L += sL[i]; C += sC[i]; }
        out[0] = L / fmaxf(C, 1.0f);
    }
}

extern "C" void kernel_launch(void* const* d_in, const int* in_sizes, int n_in,
                              void* d_out, int out_size, void* d_ws, size_t ws_size,
                              hipStream_t stream) {
    const float* x = (const float*)d_in[0];
    const float* W = (const float*)d_in[1];
    const int*   y = (const int*)d_in[2];
    float* out = (float*)d_out;

    char*  ws    = (char*)d_ws;
    float* ws_se = (float*)(ws);            // [1024] sumexp
    float* ws_sl = (float*)(ws + 4096);     // [1024] sumlogit
    float* ws_zy = (float*)(ws + 8192);     // [1024] target logit
    short* xb    = (short*)(ws + 16384);    // [1024*2048] bf16 x

    hipMemsetAsync(ws, 0, 12288, stream);

    int n4 = (NROWS * H_K) / 4;
    cvt_x_kernel<<<(n4 + 255) / 256, 256, 0, stream>>>(x, xb, n4);

    int grid = (VV / BN) * (NROWS / BM);    // 1002 * 8 = 8016
    gemm_fused<<<grid, 256, 0, stream>>>(W, xb, y, ws_se, ws_sl, ws_zy);

    finalize_kernel<<<1, 1024, 0, stream>>>(ws_se, ws_sl, ws_zy, y, out, NROWS);
}

// Round 2
// 823.647 us; speedup vs baseline: 1.5265x; 1.5265x over previous
//
#include <hip/hip_runtime.h>
#include <hip/hip_bf16.h>
#include <stdint.h>

// Problem constants (fixed by reference)
#define H_K   2048
#define VV    128256
#define NROWS 1024
#define SOFTCAP_F   30.0f
#define LS_EPS      0.1f
#define ZLOSS_SCALE 1e-4f
#define IGNORE_IDX  (-100)

// GEMM tiling: 256x128 logit tile, 4 waves (2Mx2N), wave owns 128x64
#define BM 256
#define BN 128
#define BK 64
#define NKT (H_K / BK)   // 32

typedef __attribute__((ext_vector_type(8))) short bf16x8;   // 8 bf16 = 4 VGPRs
typedef __attribute__((ext_vector_type(4))) float f32x4;

__device__ __forceinline__ short f2bf(float f) {
    __hip_bfloat16 h = __float2bfloat16(f);
    return __builtin_bit_cast(short, h);
}

__device__ __forceinline__ void gload_lds16(const void* g, void* l) {
    __builtin_amdgcn_global_load_lds(
        (const __attribute__((address_space(1))) unsigned*)g,
        (__attribute__((address_space(3))) unsigned*)l,
        16, 0, 0);
}

// ---------------- x fp32 -> bf16 conversion (4 MB, trivially mem-bound) -------------
__global__ void cvt_x_kernel(const float* __restrict__ x, short* __restrict__ xb, int n4) {
    int i = blockIdx.x * blockDim.x + threadIdx.x;
    if (i >= n4) return;
    float4 v = ((const float4*)x)[i];
    short4 h;
    h.x = f2bf(v.x); h.y = f2bf(v.y); h.z = f2bf(v.z); h.w = f2bf(v.w);
    ((short4*)xb)[i] = h;
}

// ---------------- fused GEMM + softcap + partial reductions ----------------
// C = x[1024,2048] * W^T[2048,128256], bf16 MFMA 16x16x32, fp32 acc.
// BM=256 halves issued-W vs R1; XCD-grouped ordering makes the 4 m-block
// sharers of each W col-tile consecutive on one XCD (same L2).
// B double-buffered; W reg-loads issued before COMPUTE (T14 async split).
__global__ __launch_bounds__(256, 2)
void gemm_fused(const float* __restrict__ W,
                const short* __restrict__ xb,
                const int* __restrict__ y,
                float* __restrict__ ws_se,
                float* __restrict__ ws_sl,
                float* __restrict__ ws_zy)
{
    __shared__ short As[BM * BK];        // 32 KB, swizzled, single buffer
    __shared__ short Bs[2][BN * BK];     // 2 x 16 KB, swizzled

    const int tid  = threadIdx.x;
    const int lane = tid & 63;
    const int wid  = tid >> 6;          // 0..3
    const int wm   = wid >> 1;          // wave row  (0..1) -> 128 rows each
    const int wn   = wid & 1;           // wave col  (0..1) -> 64 cols each

    // ---- XCD-grouped work order: 4008 blocks = 8 XCDs x 501 ----
    const int bid  = blockIdx.x;
    const int work = (bid & 7) * 501 + (bid >> 3);
    const int mblk = work & 3;          // NROWS/BM = 4 sharers, consecutive per XCD
    const int nblk = work >> 2;         // 0..1001
    const int row0 = mblk * BM;
    const int col0 = nblk * BN;

    // ---- A staging: 8 gload_lds (1 KB/wave each) per K-step ----
    // seg s = j*4+wid; lds byte b = s*1024 + lane*16; LDS linear, SOURCE pre-swizzled
    uintptr_t a_g[8];
    void*     a_lb[8];
    #pragma unroll
    for (int j = 0; j < 8; ++j) {
        int s    = j * 4 + wid;
        int b    = s * 1024 + lane * 16;
        int rowt = b >> 7;                               // tile-local row (128 B rows)
        int kb   = (b & 127) ^ ((rowt & 7) << 4);        // pre-swizzled k-byte
        a_g[j]  = (uintptr_t)((const char*)xb + (size_t)(row0 + rowt) * (H_K * 2) + kb);
        a_lb[j] = (char*)As + s * 1024;                  // wave-uniform base
    }

    // ---- B staging: 8x float4 W loads + cvt + swizzled ds_write per K-step ----
    uintptr_t b_g[8];
    int       b_l[8];
    #pragma unroll
    for (int j = 0; j < 8; ++j) {
        int o    = (j * 256 + tid) * 16;                 // fp32 byte in 32 KB chunk
        int rowt = o >> 8;                               // 256 B fp32 per row
        int kf   = o & 255;
        b_g[j] = (uintptr_t)((const char*)W + (size_t)(col0 + rowt) * (H_K * 4) + kf);
        int kb = (kf >> 1) ^ ((rowt & 7) << 4);          // bf16 byte, swizzled
        b_l[j] = rowt * 128 + kb;
    }

    f32x4 acc[8][4] = {};

    const int lrow = lane & 15;
    const int lkg  = lane >> 4;                 // 0..3
    const int swz  = (lrow & 7) << 4;
    char* AsB = (char*)As;

    // ---- prologue: stage tile 0 ----
    {
        float4 wv[8];
        #pragma unroll
        for (int j = 0; j < 8; ++j) wv[j] = *(const float4*)(b_g[j]);
        #pragma unroll
        for (int j = 0; j < 8; ++j) gload_lds16((const void*)a_g[j], a_lb[j]);
        #pragma unroll
        for (int j = 0; j < 8; ++j) {
            short4 h;
            h.x = f2bf(wv[j].x); h.y = f2bf(wv[j].y);
            h.z = f2bf(wv[j].z); h.w = f2bf(wv[j].w);
            *(short4*)((char*)Bs[0] + b_l[j]) = h;
        }
    }
    __syncthreads();

    for (int kt = 0; kt < NKT; ++kt) {
        const int  cur  = kt & 1;
        const bool more = (kt + 1 < NKT);

        // issue next-tile W loads early (HBM/L2 latency hides under MFMA)
        float4 wv[8];
        if (more) {
            #pragma unroll
            for (int j = 0; j < 8; ++j)
                wv[j] = *(const float4*)(b_g[j] + (size_t)(kt + 1) * (BK * 4));
        }

        // ---- COMPUTE current tile ----
        char* BsB = (char*)Bs[cur];
        #pragma unroll
        for (int ks = 0; ks < 2; ++ks) {
            bf16x8 af[8], bfv[4];
            #pragma unroll
            for (int n = 0; n < 4; ++n)
                bfv[n] = *(const bf16x8*)(BsB + (wn * 64 + n * 16 + lrow) * 128
                                              + ((ks * 64 + lkg * 16) ^ swz));
            #pragma unroll
            for (int m = 0; m < 8; ++m)
                af[m] = *(const bf16x8*)(AsB + (wm * 128 + m * 16 + lrow) * 128
                                             + ((ks * 64 + lkg * 16) ^ swz));
            #pragma unroll
            for (int m = 0; m < 8; ++m)
                #pragma unroll
                for (int n = 0; n < 4; ++n)
                    acc[m][n] = __builtin_amdgcn_mfma_f32_16x16x32_bf16(
                                    af[m], bfv[n], acc[m][n], 0, 0, 0);
        }

        // cvt + write next B tile (other buffer; safe pre-barrier)
        if (more) {
            #pragma unroll
            for (int j = 0; j < 8; ++j) {
                short4 h;
                h.x = f2bf(wv[j].x); h.y = f2bf(wv[j].y);
                h.z = f2bf(wv[j].z); h.w = f2bf(wv[j].w);
                *(short4*)((char*)Bs[cur ^ 1] + b_l[j]) = h;
            }
        }
        __syncthreads();            // As readers done; B(next) visible
        if (more) {
            #pragma unroll
            for (int j = 0; j < 8; ++j)
                gload_lds16((const void*)(a_g[j] + (size_t)(kt + 1) * (BK * 2)), a_lb[j]);
            __syncthreads();        // drain A DMA
        }
    }

    // ---- epilogue: softcap, z_y scatter, per-row partial sumexp / sumlogit ----
    // C/D layout (m89/m91): col = lane&15, row = (lane>>4)*4 + j
    #pragma unroll
    for (int m = 0; m < 8; ++m)
        #pragma unroll
        for (int n = 0; n < 4; ++n)
            #pragma unroll
            for (int j = 0; j < 4; ++j) {
                float v = acc[m][n][j];
                float e = __expf(v * (1.0f / 15.0f));           // e^{2v/30}
                acc[m][n][j] = SOFTCAP_F - 60.0f / (e + 1.0f);  // 30*tanh(v/30)
            }

    const int colw0 = col0 + wn * 64;
    #pragma unroll
    for (int m = 0; m < 8; ++m) {
        #pragma unroll
        for (int j = 0; j < 4; ++j) {
            const int grow = row0 + wm * 128 + m * 16 + lkg * 4 + j;
            // target-logit scatter (exactly one (block,thread) owns it)
            int ty = y[grow];
            int tc = ty - colw0;
            if ((unsigned)tc < 64u && (tc & 15) == lrow) {
                int nt = tc >> 4;
                float zv = (nt == 0) ? acc[m][0][j] :
                           (nt == 1) ? acc[m][1][j] :
                           (nt == 2) ? acc[m][2][j] : acc[m][3][j];
                ws_zy[grow] = zv;
            }
            // per-row partials over this wave's 64 cols
            float se = 0.f, sl = 0.f;
            #pragma unroll
            for (int n = 0; n < 4; ++n) {
                float v = acc[m][n][j];
                sl += v;
                se += __expf(v);     // |logits| <= 30 -> no max-shift needed
            }
            #pragma unroll
            for (int d = 1; d < 16; d <<= 1) {
                se += __shfl_xor(se, d, 64);
                sl += __shfl_xor(sl, d, 64);
            }
            if (lrow == 0) {
                atomicAdd(&ws_se[grow], se);
                atomicAdd(&ws_sl[grow], sl);
            }
        }
    }
}

// ---------------- finalize: per-token loss + mean ----------------
__global__ void finalize_kernel(const float* __restrict__ ws_se,
                                const float* __restrict__ ws_sl,
                                const float* __restrict__ ws_zy,
                                const int* __restrict__ y,
                                float* __restrict__ out, int n)
{
    __shared__ float sL[16], sC[16];
    const int tid = threadIdx.x;
    float loss = 0.f, cnt = 0.f;
    if (tid < n) {
        int ty = y[tid];
        if (ty != IGNORE_IDX) {
            float lse = logf(ws_se[tid]);
            float ce  = lse - (1.0f - LS_EPS) * ws_zy[tid]
                          - (LS_EPS / (float)VV) * ws_sl[tid];
            loss = ce + ZLOSS_SCALE * lse * lse;
            cnt  = 1.f;
        }
    }
    #pragma unroll
    for (int d = 32; d >= 1; d >>= 1) {
        loss += __shfl_down(loss, d, 64);
        cnt  += __shfl_down(cnt,  d, 64);
    }
    const int w = tid >> 6;
    if ((tid & 63) == 0) { sL[w] = loss; sC[w] = cnt; }
    __syncthreads();
    if (tid == 0) {
        float L = 0.f, C = 0.f;
        #pragma unroll
        for (int i = 0; i < 16; ++i) { L += sL[i]; C += sC[i]; }
        out[0] = L / fmaxf(C, 1.0f);
    }
}

extern "C" void kernel_launch(void* const* d_in, const int* in_sizes, int n_in,
                              void* d_out, int out_size, void* d_ws, size_t ws_size,
                              hipStream_t stream) {
    const float* x = (const float*)d_in[0];
    const float* W = (const float*)d_in[1];
    const int*   y = (const int*)d_in[2];
    float* out = (float*)d_out;

    char*  ws    = (char*)d_ws;
    float* ws_se = (float*)(ws);            // [1024] sumexp
    float* ws_sl = (float*)(ws + 4096);     // [1024] sumlogit
    float* ws_zy = (float*)(ws + 8192);     // [1024] target logit
    short* xb    = (short*)(ws + 16384);    // [1024*2048] bf16 x

    hipMemsetAsync(ws, 0, 12288, stream);

    int n4 = (NROWS * H_K) / 4;
    cvt_x_kernel<<<(n4 + 255) / 256, 256, 0, stream>>>(x, xb, n4);

    int grid = (VV / BN) * (NROWS / BM);    // 1002 * 4 = 4008
    gemm_fused<<<grid, 256, 0, stream>>>(W, xb, y, ws_se, ws_sl, ws_zy);

    finalize_kernel<<<1, 1024, 0, stream>>>(ws_se, ws_sl, ws_zy, y, out, NROWS);
}

// Round 4
// 746.478 us; speedup vs baseline: 1.6843x; 1.1034x over previous
//
#include <hip/hip_runtime.h>
#include <hip/hip_bf16.h>
#include <stdint.h>

// Problem constants (fixed by reference)
#define H_K   2048
#define VV    128256
#define NROWS 1024
#define SOFTCAP_F   30.0f
#define LS_EPS      0.1f
#define ZLOSS_SCALE 1e-4f
#define IGNORE_IDX  (-100)

// GEMM tiling: 256x256 logit tile, 8 waves (2M x 4N), wave owns 128x64
#define BM 256
#define BN 256
#define BK 32
#define NKT (H_K / BK)   // 64
#define THREADS 512

typedef __attribute__((ext_vector_type(8))) short bf16x8;   // 8 bf16 = 4 VGPRs
typedef __attribute__((ext_vector_type(4))) float f32x4;

__device__ __forceinline__ short f2bf(float f) {
    __hip_bfloat16 h = __float2bfloat16(f);
    return __builtin_bit_cast(short, h);
}

__device__ __forceinline__ void gload_lds16(const void* g, void* l) {
    __builtin_amdgcn_global_load_lds(
        (const __attribute__((address_space(1))) unsigned*)g,
        (__attribute__((address_space(3))) unsigned*)l,
        16, 0, 0);
}

#define SBAR0     __builtin_amdgcn_sched_barrier(0)
#define WAITVM(N) do { asm volatile("s_waitcnt vmcnt(" #N ")" ::: "memory"); SBAR0; } while (0)
#define WAITLG    do { asm volatile("s_waitcnt lgkmcnt(0)" ::: "memory"); SBAR0; } while (0)

// LDS layout (A and B tiles, 256 rows x 64 B): super-row = row pair (128 B).
// addr(row,kb) = (row>>1)*128 + ((row&1)<<6) + (kb ^ (((row>>1)&3)<<4))
// -> 16-lane b128 read groups hit 8 distinct 16-B slots (2-way residual = free).

// ---------------- x fp32 -> bf16 conversion (12 MB traffic) -------------
__global__ void cvt_x_kernel(const float* __restrict__ x, short* __restrict__ xb, int n4) {
    int i = blockIdx.x * blockDim.x + threadIdx.x;
    if (i >= n4) return;
    float4 v = ((const float4*)x)[i];
    short4 h;
    h.x = f2bf(v.x); h.y = f2bf(v.y); h.z = f2bf(v.z); h.w = f2bf(v.w);
    ((short4*)xb)[i] = h;
}

// ---------------- fused GEMM + softcap + partial reductions ----------------
// 2-phase-per-K-tile, counted vmcnt (T3+T4), super-row swizzle (T2), setprio (T5).
// Steady state per iter: issue [A-DMA(t+1)x2, W(t+2)x4]; mid vmcnt(6) releases
// W(t+1) for cvt+ds_write; vmcnt(4) BEFORE end barrier proves A(t+1) landed in
// every wave (cross-wave RAW safe). Never drains to 0 in the main loop.
__global__ __launch_bounds__(THREADS, 2)
void gemm_fused(const float* __restrict__ W,
                const short* __restrict__ xb,
                const int* __restrict__ y,
                float* __restrict__ ws_se,
                float* __restrict__ ws_sl,
                float* __restrict__ ws_zy)
{
    __shared__ short As[2][BM * BK];   // 2 x 16 KB
    __shared__ short Bs[2][BN * BK];   // 2 x 16 KB   (64 KB total)

    const int tid  = threadIdx.x;
    const int lane = tid & 63;
    const int wid  = tid >> 6;          // 0..7
    const int wm   = wid >> 2;          // 0..1  -> 128 rows
    const int wn   = wid & 3;           // 0..3  -> 64 cols

    // ---- bijective XCD swizzle: nwg = 2004 = 8*250+4 (m204) ----
    const int bid  = blockIdx.x;
    const int xcd  = bid & 7, o8 = bid >> 3;
    const int work = (xcd < 4 ? xcd * 251 : 1004 + (xcd - 4) * 250) + o8;
    const int mblk = work & 3;          // 4 m-sharers consecutive per XCD
    const int nblk = work >> 2;
    const int row0 = mblk * BM;
    const int col0 = nblk * BN;

    // ---- A staging (global_load_lds, src pre-swizzled; LDS linear dest) ----
    // seg s = {wid, 8+wid}; lane's LDS byte = s*1024 + lane*16
    // inverse: R = s*8 + lane>>3; row = 2R + ((lane>>2)&1);
    //          kb = ((lane&3)*16) ^ (((lane>>3)&3)<<4)
    uintptr_t agb0, agb1;
    char *al0, *al1;
    {
        int Rb   = (lane >> 3);
        int rlo  = (lane >> 2) & 1;
        int kb   = ((lane & 3) * 16) ^ (((lane >> 3) & 3) << 4);
        int row_0 = (wid * 8 + Rb) * 2 + rlo;          // seg wid
        int row_1 = ((8 + wid) * 8 + Rb) * 2 + rlo;    // seg 8+wid
        agb0 = (uintptr_t)((const char*)xb + (size_t)(row0 + row_0) * (H_K * 2) + kb);
        agb1 = (uintptr_t)((const char*)xb + (size_t)(row0 + row_1) * (H_K * 2) + kb);
        al0  = (char*)As + wid * 1024;
        al1  = (char*)As + (8 + wid) * 1024;
    }

    // ---- B staging (reg-staged W fp32 -> bf16, swizzled ds_write_b64) ----
    // thread: rowt = tid>>3 (+64 per j), fp32 bytes kf = (tid&7)*16 -> bf16 kb8 = (tid&7)*8
    uintptr_t wgb;
    int bl0;
    {
        int rt  = tid >> 3;
        int kf  = (tid & 7) * 16;
        wgb = (uintptr_t)((const char*)W + (size_t)(col0 + rt) * (H_K * 4) + kf);
        int kb8 = (tid & 7) * 8;
        bl0 = (rt >> 1) * 128 + ((rt & 1) << 6) + (kb8 ^ (((rt >> 1) & 3) << 4));
        // j: +64 rows -> lds +4096 ; global +524288
    }

    // ---- MFMA read offsets ----
    const int lrow = lane & 15;
    const int lkg  = lane >> 4;                 // 0..3
    const int key  = ((lrow >> 1) & 3) << 4;
    const int rA   = wm * 128 + lrow;
    const int rB   = wn * 64 + lrow;
    const int aOff0 = (rA >> 1) * 128 + ((rA & 1) << 6) + ((lkg * 16) ^ key); // +1024*m
    const int bOff0 = (rB >> 1) * 128 + ((rB & 1) << 6) + ((lkg * 16) ^ key); // +1024*n

    f32x4 acc[8][4] = {};
    float4 wvA[4], wvB[4];

    // ---- prologue: stage tile 0; preload W(1) into wvA; full drain ----
    {
        float4 w0[4];
        #pragma unroll
        for (int j = 0; j < 4; ++j)
            w0[j] = *(const float4*)(wgb + (size_t)j * 524288);
        gload_lds16((const void*)agb0, al0);
        gload_lds16((const void*)agb1, al1);
        #pragma unroll
        for (int j = 0; j < 4; ++j)
            wvA[j] = *(const float4*)(wgb + 128 + (size_t)j * 524288);
        char* B0 = (char*)Bs;
        #pragma unroll
        for (int j = 0; j < 4; ++j) {
            short4 h;
            h.x = f2bf(w0[j].x); h.y = f2bf(w0[j].y);
            h.z = f2bf(w0[j].z); h.w = f2bf(w0[j].w);
            *(short4*)(B0 + bl0 + j * 4096) = h;
        }
        __syncthreads();   // drains vm+lgkm; counted model starts clean
    }

#define MFM(mi,ni,AF,BV) acc[mi][ni] = __builtin_amdgcn_mfma_f32_16x16x32_bf16(AF, BV, acc[mi][ni], 0, 0, 0)

#define K_ITER(tt, CUR, WC, WI, ISSA, ISSW, DOCVT, VMM, VME) do { \
    const char* Ab_ = ((const char*)As) + (CUR) * 16384; \
    const char* Bb_ = ((const char*)Bs) + (CUR) * 16384; \
    bf16x8 b0_ = *(const bf16x8*)(Bb_ + bOff0); \
    bf16x8 b1_ = *(const bf16x8*)(Bb_ + bOff0 + 1024); \
    bf16x8 b2_ = *(const bf16x8*)(Bb_ + bOff0 + 2048); \
    bf16x8 b3_ = *(const bf16x8*)(Bb_ + bOff0 + 3072); \
    bf16x8 a0_ = *(const bf16x8*)(Ab_ + aOff0); \
    bf16x8 a1_ = *(const bf16x8*)(Ab_ + aOff0 + 1024); \
    bf16x8 a2_ = *(const bf16x8*)(Ab_ + aOff0 + 2048); \
    bf16x8 a3_ = *(const bf16x8*)(Ab_ + aOff0 + 3072); \
    SBAR0; \
    if (ISSA) { \
        gload_lds16((const void*)(agb0 + (size_t)((tt)+1) * 64), al0 + (((CUR)^1) * 16384)); \
        gload_lds16((const void*)(agb1 + (size_t)((tt)+1) * 64), al1 + (((CUR)^1) * 16384)); \
        SBAR0; \
    } \
    if (ISSW) { \
        WI[0] = *(const float4*)(wgb + (size_t)((tt)+2) * 128); \
        WI[1] = *(const float4*)(wgb + (size_t)((tt)+2) * 128 +  524288); \
        WI[2] = *(const float4*)(wgb + (size_t)((tt)+2) * 128 + 1048576); \
        WI[3] = *(const float4*)(wgb + (size_t)((tt)+2) * 128 + 1572864); \
        SBAR0; \
    } \
    __builtin_amdgcn_s_barrier(); \
    WAITLG; \
    __builtin_amdgcn_s_setprio(1); \
    MFM(0,0,a0_,b0_); MFM(0,1,a0_,b1_); MFM(0,2,a0_,b2_); MFM(0,3,a0_,b3_); \
    MFM(1,0,a1_,b0_); MFM(1,1,a1_,b1_); MFM(1,2,a1_,b2_); MFM(1,3,a1_,b3_); \
    MFM(2,0,a2_,b0_); MFM(2,1,a2_,b1_); MFM(2,2,a2_,b2_); MFM(2,3,a2_,b3_); \
    MFM(3,0,a3_,b0_); MFM(3,1,a3_,b1_); MFM(3,2,a3_,b2_); MFM(3,3,a3_,b3_); \
    __builtin_amdgcn_s_setprio(0); \
    SBAR0; \
    a0_ = *(const bf16x8*)(Ab_ + aOff0 + 4096); \
    a1_ = *(const bf16x8*)(Ab_ + aOff0 + 5120); \
    a2_ = *(const bf16x8*)(Ab_ + aOff0 + 6144); \
    a3_ = *(const bf16x8*)(Ab_ + aOff0 + 7168); \
    SBAR0; \
    WAITVM(VMM); \
    if (DOCVT) { \
        char* Bn_ = ((char*)Bs) + (((CUR)^1) * 16384); \
        short4 h_; \
        h_.x=f2bf(WC[0].x); h_.y=f2bf(WC[0].y); h_.z=f2bf(WC[0].z); h_.w=f2bf(WC[0].w); \
        *(short4*)(Bn_ + bl0        ) = h_; \
        h_.x=f2bf(WC[1].x); h_.y=f2bf(WC[1].y); h_.z=f2bf(WC[1].z); h_.w=f2bf(WC[1].w); \
        *(short4*)(Bn_ + bl0 +  4096) = h_; \
        h_.x=f2bf(WC[2].x); h_.y=f2bf(WC[2].y); h_.z=f2bf(WC[2].z); h_.w=f2bf(WC[2].w); \
        *(short4*)(Bn_ + bl0 +  8192) = h_; \
        h_.x=f2bf(WC[3].x); h_.y=f2bf(WC[3].y); h_.z=f2bf(WC[3].z); h_.w=f2bf(WC[3].w); \
        *(short4*)(Bn_ + bl0 + 12288) = h_; \
        SBAR0; \
    } \
    WAITLG; \
    __builtin_amdgcn_s_setprio(1); \
    MFM(4,0,a0_,b0_); MFM(4,1,a0_,b1_); MFM(4,2,a0_,b2_); MFM(4,3,a0_,b3_); \
    MFM(5,0,a1_,b0_); MFM(5,1,a1_,b1_); MFM(5,2,a1_,b2_); MFM(5,3,a1_,b3_); \
    MFM(6,0,a2_,b0_); MFM(6,1,a2_,b1_); MFM(6,2,a2_,b2_); MFM(6,3,a2_,b3_); \
    MFM(7,0,a3_,b0_); MFM(7,1,a3_,b1_); MFM(7,2,a3_,b2_); MFM(7,3,a3_,b3_); \
    __builtin_amdgcn_s_setprio(0); \
    SBAR0; \
    WAITVM(VME); \
    __builtin_amdgcn_s_barrier(); \
} while (0)

    // main loop: t = 0..61 (parity-unrolled x2), then peel t=62, t=63
    #pragma unroll 1
    for (int t2 = 0; t2 < 31; ++t2) {
        const int te = 2 * t2;
        K_ITER(te,     0, wvA, wvB, 1, 1, 1, 6, 4);
        K_ITER(te + 1, 1, wvB, wvA, 1, 1, 1, 6, 4);
    }
    K_ITER(62, 0, wvA, wvB, 1, 0, 1, 2, 0);
    K_ITER(63, 1, wvB, wvA, 0, 0, 0, 0, 0);

    // ---- epilogue: softcap, z_y scatter, per-row partial sumexp / sumlogit ----
    // C/D layout (m89/m91): col = lane&15, row = (lane>>4)*4 + j
    #pragma unroll
    for (int m = 0; m < 8; ++m)
        #pragma unroll
        for (int n = 0; n < 4; ++n)
            #pragma unroll
            for (int j = 0; j < 4; ++j) {
                float v = acc[m][n][j];
                float e = __expf(v * (1.0f / 15.0f));           // e^{2v/30}
                acc[m][n][j] = SOFTCAP_F - 60.0f / (e + 1.0f);  // 30*tanh(v/30)
            }

    const int colw0 = col0 + wn * 64;
    #pragma unroll
    for (int m = 0; m < 8; ++m) {
        #pragma unroll
        for (int j = 0; j < 4; ++j) {
            const int grow = row0 + wm * 128 + m * 16 + lkg * 4 + j;
            int ty = y[grow];
            int tc = ty - colw0;
            if ((unsigned)tc < 64u && (tc & 15) == lrow) {
                int nt = tc >> 4;
                float zv = (nt == 0) ? acc[m][0][j] :
                           (nt == 1) ? acc[m][1][j] :
                           (nt == 2) ? acc[m][2][j] : acc[m][3][j];
                ws_zy[grow] = zv;
            }
            float se = 0.f, sl = 0.f;
            #pragma unroll
            for (int n = 0; n < 4; ++n) {
                float v = acc[m][n][j];
                sl += v;
                se += __expf(v);     // |logits| <= 30 -> no max-shift needed
            }
            #pragma unroll
            for (int d = 1; d < 16; d <<= 1) {
                se += __shfl_xor(se, d, 64);
                sl += __shfl_xor(sl, d, 64);
            }
            if (lrow == 0) {
                atomicAdd(&ws_se[grow], se);
                atomicAdd(&ws_sl[grow], sl);
            }
        }
    }
}

// ---------------- finalize: per-token loss + mean ----------------
__global__ void finalize_kernel(const float* __restrict__ ws_se,
                                const float* __restrict__ ws_sl,
                                const float* __restrict__ ws_zy,
                                const int* __restrict__ y,
                                float* __restrict__ out, int n)
{
    __shared__ float sL[16], sC[16];
    const int tid = threadIdx.x;
    float loss = 0.f, cnt = 0.f;
    if (tid < n) {
        int ty = y[tid];
        if (ty != IGNORE_IDX) {
            float lse = logf(ws_se[tid]);
            float ce  = lse - (1.0f - LS_EPS) * ws_zy[tid]
                          - (LS_EPS / (float)VV) * ws_sl[tid];
            loss = ce + ZLOSS_SCALE * lse * lse;
            cnt  = 1.f;
        }
    }
    #pragma unroll
    for (int d = 32; d >= 1; d >>= 1) {
        loss += __shfl_down(loss, d, 64);
        cnt  += __shfl_down(cnt,  d, 64);
    }
    const int w = tid >> 6;
    if ((tid & 63) == 0) { sL[w] = loss; sC[w] = cnt; }
    __syncthreads();
    if (tid == 0) {
        float L = 0.f, C = 0.f;
        #pragma unroll
        for (int i = 0; i < 16; ++i) { L += sL[i]; C += sC[i]; }
        out[0] = L / fmaxf(C, 1.0f);
    }
}

extern "C" void kernel_launch(void* const* d_in, const int* in_sizes, int n_in,
                              void* d_out, int out_size, void* d_ws, size_t ws_size,
                              hipStream_t stream) {
    const float* x = (const float*)d_in[0];
    const float* W = (const float*)d_in[1];
    const int*   y = (const int*)d_in[2];
    float* out = (float*)d_out;

    char*  ws    = (char*)d_ws;
    float* ws_se = (float*)(ws);            // [1024] sumexp
    float* ws_sl = (float*)(ws + 4096);     // [1024] sumlogit
    float* ws_zy = (float*)(ws + 8192);     // [1024] target logit
    short* xb    = (short*)(ws + 16384);    // [1024*2048] bf16 x

    hipMemsetAsync(ws, 0, 12288, stream);

    int n4 = (NROWS * H_K) / 4;
    cvt_x_kernel<<<(n4 + 255) / 256, 256, 0, stream>>>(x, xb, n4);

    int grid = (VV / BN) * (NROWS / BM);    // 501 * 4 = 2004
    gemm_fused<<<grid, THREADS, 0, stream>>>(W, xb, y, ws_se, ws_sl, ws_zy);

    finalize_kernel<<<1, 1024, 0, stream>>>(ws_se, ws_sl, ws_zy, y, out, NROWS);
}